// Round 7
// baseline (6374.964 us; speedup 1.0000x reference)
//
#include <hip/hip_runtime.h>

// SNN layer: currents[t,b,o] = sum_i x[b,i,t] * w[i,o] in fp64 (binary spike output
// demands decision-exactness vs the numpy fp64 ref), then sequential LIF scan.
//
// Round 7:
//  - KI 16 -> 32: halves the number of barrier-drain stages (r6: MfmaUtil 84.5%,
//    ~22% of GEMM time = all-resident-blocks drained at barriers).
//  - __launch_bounds__(256,4): 4 blocks/CU (LDS 2x17.4KB x4 = 139KB <= 160KB) so a
//    4th block covers each drain.
//  - Explicit register prefetch of the next K-stage issued right after the barrier:
//    HBM latency (~900cy) overlaps the ~4096-cycle MFMA block.
//  - Scan: 32-step double-buffer (issue next 32 loads one full iteration early,
//    ~8.4MB in flight > 5.7MB BW*latency product). r6's LDS transpose reverted
//    (regressed ~26us; 1-wave flush barriers cost more than uncoalesced stores).
//  - NOTE: SQ_LDS_BANK_CONFLICT pegged at exactly 2^25 in r4-r6 -> saturated
//    counter, not signal. Padding kept (costless, proven neutral).
//
// ws layout: [0, 256KB)   : v-state, 32*1024 doubles (carried across T-chunks)
//            [256KB, ...) : current chunk buffer, Tc * 32 * 1024 doubles

#define NB 32
#define NI 1024
#define NO 1024
#define NT 1000
#define TT 128   // t-tile per block
#define OT 128   // o-tile per block
#define KI 32    // k (i) tile
#define LP 8     // LDS row pad: stride 136 = 8 mod 32 banks

typedef double d4 __attribute__((ext_vector_type(4)));

__global__ __launch_bounds__(256, 4)
void snn_gemm_mfma64(const float* __restrict__ x, const float* __restrict__ w,
                     double* __restrict__ cur, int t0, int len)
{
    __shared__ float As[KI][TT + LP];   // 17.4 KB (i-major, t contiguous)
    __shared__ float Bs[KI][OT + LP];   // 17.4 KB (i-major, o contiguous)

    const int tid  = threadIdx.x;
    const int lane = tid & 63;
    const int wave = tid >> 6;           // 4 waves: 2x2 grid of 64x64 wave tiles
    const int wm   = (wave >> 1) * 64;   // t offset within block tile
    const int wn   = (wave & 1) * 64;    // o offset within block tile
    const int m16  = lane & 15;
    const int kq   = lane >> 4;          // 0..3

    const int tt0 = t0 + blockIdx.x * TT;
    const int o0  = blockIdx.y * OT;
    const int b   = blockIdx.z;
    const float* xb = x + (size_t)b * NI * NT;

    // ---- probe the D register->element mapping of v_mfma_f64_16x16x4f64 ----
    // A = identity (4 K-slices), B[k][n] = 100k+n+1  =>  D[m][n] = 100m+n+1.
    // Exact small integers in fp64 -> each lane decodes (row,col) per acc register.
    d4 p = (d4)0.0;
#pragma unroll
    for (int s = 0; s < 4; ++s) {
        const double ap = (m16 == kq + 4 * s) ? 1.0 : 0.0;        // A[m=lane&15][k=lane>>4]
        const double bp = (double)(100 * (kq + 4 * s) + m16 + 1); // B[k=lane>>4][n=lane&15]
        p = __builtin_amdgcn_mfma_f64_16x16x4f64(ap, bp, p, 0, 0, 0);
    }
    int prow[4], pcol[4];
#pragma unroll
    for (int r = 0; r < 4; ++r) {
        const int val = ((int)p[r] - 1) & 0xffff;  // 100*m + n
        const int m = val / 100;
        prow[r] = m & 15;
        pcol[r] = (val - m * 100) & 15;
    }

    d4 acc[4][4];   // [t-tile][o-tile] -> AGPRs
#pragma unroll
    for (int r = 0; r < 4; ++r)
#pragma unroll
        for (int c = 0; c < 4; ++c) acc[r][c] = (d4)0.0;

    // staging: 32 rows x 128 cols per matrix, 4 float4 per thread per matrix
    const int sr = tid >> 5;         // rows sr + 8j, j=0..3
    const int sc = (tid & 31) * 4;   // 0,4,...,124
    const int at = tt0 + sc;
    const bool a_ok = (at < NT);     // NT%4==0, at%4==0 -> whole float4 in bounds

    float4 pa[4], pb[4];
#pragma unroll
    for (int j = 0; j < 4; ++j) {
        pa[j] = a_ok ? *(const float4*)(xb + (size_t)(sr + 8 * j) * NT + at)
                     : make_float4(0.f, 0.f, 0.f, 0.f);
        pb[j] = *(const float4*)(w + (size_t)(sr + 8 * j) * NO + (o0 + sc));
    }

    for (int i0 = 0; i0 < NI; i0 += KI) {
        __syncthreads();   // previous stage's LDS reads done
#pragma unroll
        for (int j = 0; j < 4; ++j) {
            *(float4*)&As[sr + 8 * j][sc] = pa[j];
            *(float4*)&Bs[sr + 8 * j][sc] = pb[j];
        }
        __syncthreads();

        // issue next stage's global loads now; they overlap the MFMA block below
        if (i0 + KI < NI) {
            const int i1 = i0 + KI;
#pragma unroll
            for (int j = 0; j < 4; ++j) {
                pa[j] = a_ok ? *(const float4*)(xb + (size_t)(i1 + sr + 8 * j) * NT + at)
                             : make_float4(0.f, 0.f, 0.f, 0.f);
                pb[j] = *(const float4*)(w + (size_t)(i1 + sr + 8 * j) * NO + (o0 + sc));
            }
        }

#pragma unroll
        for (int k4 = 0; k4 < KI / 4; ++k4) {
            const int kk = k4 * 4 + kq;
            double af[4], bf[4];
#pragma unroll
            for (int r = 0; r < 4; ++r) af[r] = (double)As[kk][wm + r * 16 + m16];
#pragma unroll
            for (int c = 0; c < 4; ++c) bf[c] = (double)Bs[kk][wn + c * 16 + m16];
#pragma unroll
            for (int r = 0; r < 4; ++r)
#pragma unroll
                for (int c = 0; c < 4; ++c)
                    acc[r][c] = __builtin_amdgcn_mfma_f64_16x16x4f64(
                        af[r], bf[c], acc[r][c], 0, 0, 0);
        }
    }

    // store via probed mapping: acc[rt][ct][j] holds D_tile[prow[j]][pcol[j]]
    const int tend = t0 + len;
#pragma unroll
    for (int rt = 0; rt < 4; ++rt) {
#pragma unroll
        for (int j = 0; j < 4; ++j) {
            const int tg = tt0 + wm + rt * 16 + prow[j];
            if (tg < tend) {
                double* dst = cur + ((size_t)(tg - t0) * NB + b) * NO + o0 + wn;
#pragma unroll
                for (int ct = 0; ct < 4; ++ct)
                    dst[ct * 16 + pcol[j]] = acc[rt][ct][j];
            }
        }
    }
}

// LIF scan: one thread per (b,o); cur chunk is [tc][b*NO+o] fp64 (wave reads 512B
// contiguous per t-step). 32-step double buffer: next block's 32 loads are issued
// one full iteration before use -> ~8.4MB in flight across the grid (> BW*latency).
#define NC 32
__global__ __launch_bounds__(64)
void snn_scan_f64(const double* __restrict__ cur, float* __restrict__ out,
                  double* __restrict__ vstate, int t0, int len)
{
    const int gid = blockIdx.x * 64 + threadIdx.x;   // b*NO + o
    const double dt = 0.001 / 50.0;                  // MS / TAU, IEEE double

    double v = (t0 == 0) ? 0.0 : vstate[gid];
    const double* cp = cur + gid;                    // stride NB*NO per t-step
    float* op = out + (size_t)gid * NT + t0;         // thread-contiguous in t

    const size_t ts = (size_t)NB * NO;               // 32768
    const int nb = len / NC;                         // full 32-blocks
    const int rem = len - nb * NC;                   // tail (multiple of 8)

    double A[NC], B[NC];
#pragma unroll
    for (int j = 0; j < NC; ++j) A[j] = (j < len) ? cp[(size_t)j * ts] : 0.0;

    for (int blk = 0; blk < nb; ++blk) {
        const int next = (blk + 1) * NC;
#pragma unroll
        for (int j = 0; j < NC; ++j)
            B[j] = (next + j < len) ? cp[(size_t)(next + j) * ts] : 0.0;

#pragma unroll
        for (int q = 0; q < NC; q += 8) {
            float s[8];
#pragma unroll
            for (int j = 0; j < 8; ++j) {
                v = v + (A[q + j] - v) * dt;
                const bool sp = (v >= 1.0);
                s[j] = sp ? 1.0f : 0.0f;
                if (sp) v = 0.0;
            }
            *(float4*)(op + q)     = make_float4(s[0], s[1], s[2], s[3]);
            *(float4*)(op + q + 4) = make_float4(s[4], s[5], s[6], s[7]);
        }
        op += NC;
#pragma unroll
        for (int j = 0; j < NC; ++j) A[j] = B[j];
    }

    for (int q = 0; q < rem; q += 8) {               // tail (data already in A)
        float s[8];
#pragma unroll
        for (int j = 0; j < 8; ++j) {
            v = v + (A[q + j] - v) * dt;
            const bool sp = (v >= 1.0);
            s[j] = sp ? 1.0f : 0.0f;
            if (sp) v = 0.0;
        }
        *(float4*)(op + q)     = make_float4(s[0], s[1], s[2], s[3]);
        *(float4*)(op + q + 4) = make_float4(s[4], s[5], s[6], s[7]);
    }
    vstate[gid] = v;
}

extern "C" void kernel_launch(void* const* d_in, const int* in_sizes, int n_in,
                              void* d_out, int out_size, void* d_ws, size_t ws_size,
                              hipStream_t stream)
{
    const float* x = (const float*)d_in[0];
    const float* w = (const float*)d_in[1];
    float* out = (float*)d_out;

    const size_t vbytes = (size_t)NB * NO * sizeof(double);   // 256 KB
    double* vstate = (double*)d_ws;
    double* curbuf = (double*)((char*)d_ws + vbytes);

    const size_t per_t = (size_t)NB * NO * sizeof(double);    // 256 KB per t-step
    size_t avail = (ws_size > vbytes) ? (ws_size - vbytes) : 0;
    int Tc = (int)((avail / per_t < (size_t)NT) ? (avail / per_t) : (size_t)NT);
    Tc &= ~7;                 // multiple of 8 (scan tail granularity)
    if (Tc < 8) Tc = 8;

    for (int t0 = 0; t0 < NT; t0 += Tc) {
        const int len = (NT - t0 < Tc) ? (NT - t0) : Tc;
        dim3 gg((len + TT - 1) / TT, NO / OT, NB);
        snn_gemm_mfma64<<<gg, 256, 0, stream>>>(x, w, curbuf, t0, len);
        snn_scan_f64<<<(NB * NO) / 64, 64, 0, stream>>>(curbuf, out, vstate, t0, len);
    }
}

// Round 8
// 1293.974 us; speedup vs baseline: 4.9267x; 4.9267x over previous
//
#include <hip/hip_runtime.h>

// SNN layer: currents[t,b,o] = sum_i x[b,i,t] * w[i,o] in fp64 (binary spike output
// demands decision-exactness vs the numpy fp64 ref), then sequential LIF scan.
//
// Round 8 = proven r5 GEMM + r7 scan:
//  - GEMM: KI=16, __launch_bounds__(256,3), float LDS, cvt at fragment read,
//    probe-calibrated f64 MFMA D layout. r5 measured: 1115us, MfmaUtil 85.4%.
//    r7's lesson: acc needs 128 unified regs -> bounds(256,4) or KI=32+prefetch
//    forces spills (hbm_bytes 0.45GB -> 29.6GB). Do not exceed 3 blocks/CU here.
//  - Scan: NC=32 double-buffer (next 32 loads issued a full iteration early ->
//    ~8.4MB in flight > BW*latency product; 128B contiguous stores per thread per
//    iter -> full-line writes, no amplification).
//  - SQ_LDS_BANK_CONFLICT pegs at 2^25 every round regardless of layout ->
//    saturated counter, ignore it.
//
// ws layout: [0, 256KB)   : v-state, 32*1024 doubles (carried across T-chunks)
//            [256KB, ...) : current chunk buffer, Tc * 32 * 1024 doubles

#define NB 32
#define NI 1024
#define NO 1024
#define NT 1000
#define TT 128   // t-tile per block
#define OT 128   // o-tile per block
#define KI 16    // k (i) tile

typedef double d4 __attribute__((ext_vector_type(4)));

__global__ __launch_bounds__(256, 3)
void snn_gemm_mfma64(const float* __restrict__ x, const float* __restrict__ w,
                     double* __restrict__ cur, int t0, int len)
{
    __shared__ float As[KI][TT];   // 8 KB (i-major, t contiguous)
    __shared__ float Bs[KI][OT];   // 8 KB (i-major, o contiguous)

    const int tid  = threadIdx.x;
    const int lane = tid & 63;
    const int wave = tid >> 6;           // 4 waves: 2x2 grid of 64x64 wave tiles
    const int wm   = (wave >> 1) * 64;   // t offset within block tile
    const int wn   = (wave & 1) * 64;    // o offset within block tile
    const int m16  = lane & 15;
    const int kq   = lane >> 4;          // 0..3

    const int tt0 = t0 + blockIdx.x * TT;
    const int o0  = blockIdx.y * OT;
    const int b   = blockIdx.z;
    const float* xb = x + (size_t)b * NI * NT;

    // ---- probe the D register->element mapping of v_mfma_f64_16x16x4f64 ----
    // A = identity (4 K-slices), B[k][n] = 100k+n+1  =>  D[m][n] = 100m+n+1.
    // Exact small integers in fp64 -> each lane decodes (row,col) per acc register.
    d4 p = (d4)0.0;
#pragma unroll
    for (int s = 0; s < 4; ++s) {
        const double ap = (m16 == kq + 4 * s) ? 1.0 : 0.0;        // A[m=lane&15][k=lane>>4]
        const double bp = (double)(100 * (kq + 4 * s) + m16 + 1); // B[k=lane>>4][n=lane&15]
        p = __builtin_amdgcn_mfma_f64_16x16x4f64(ap, bp, p, 0, 0, 0);
    }
    int prow[4], pcol[4];
#pragma unroll
    for (int r = 0; r < 4; ++r) {
        const int val = ((int)p[r] - 1) & 0xffff;  // 100*m + n
        const int m = val / 100;
        prow[r] = m & 15;
        pcol[r] = (val - m * 100) & 15;
    }

    d4 acc[4][4];   // [t-tile][o-tile] -> AGPRs
#pragma unroll
    for (int r = 0; r < 4; ++r)
#pragma unroll
        for (int c = 0; c < 4; ++c) acc[r][c] = (d4)0.0;

    // staging: 16 rows x 128 cols per matrix, 2 float4 per thread per matrix
    const int sr = tid >> 5;         // rows sr and sr+8
    const int sc = (tid & 31) * 4;   // 0,4,...,124
    const int at = tt0 + sc;

    for (int i0 = 0; i0 < NI; i0 += KI) {
        float4 a0 = make_float4(0.f, 0.f, 0.f, 0.f);
        float4 a1 = a0;
        if (at < NT) {   // NT%4==0, at%4==0 -> whole float4 in bounds when at<NT
            a0 = *(const float4*)(xb + (size_t)(i0 + sr) * NT + at);
            a1 = *(const float4*)(xb + (size_t)(i0 + sr + 8) * NT + at);
        }
        const float4 b0 = *(const float4*)(w + (size_t)(i0 + sr) * NO + (o0 + sc));
        const float4 b1 = *(const float4*)(w + (size_t)(i0 + sr + 8) * NO + (o0 + sc));

        __syncthreads();   // previous iteration's LDS reads done
        *(float4*)&As[sr][sc]     = a0;
        *(float4*)&As[sr + 8][sc] = a1;
        *(float4*)&Bs[sr][sc]     = b0;
        *(float4*)&Bs[sr + 8][sc] = b1;
        __syncthreads();

#pragma unroll
        for (int k4 = 0; k4 < 4; ++k4) {
            const int kk = k4 * 4 + kq;
            double af[4], bf[4];
#pragma unroll
            for (int r = 0; r < 4; ++r) af[r] = (double)As[kk][wm + r * 16 + m16];
#pragma unroll
            for (int c = 0; c < 4; ++c) bf[c] = (double)Bs[kk][wn + c * 16 + m16];
#pragma unroll
            for (int r = 0; r < 4; ++r)
#pragma unroll
                for (int c = 0; c < 4; ++c)
                    acc[r][c] = __builtin_amdgcn_mfma_f64_16x16x4f64(
                        af[r], bf[c], acc[r][c], 0, 0, 0);
        }
    }

    // store via probed mapping: acc[rt][ct][j] holds D_tile[prow[j]][pcol[j]]
    const int tend = t0 + len;
#pragma unroll
    for (int rt = 0; rt < 4; ++rt) {
#pragma unroll
        for (int j = 0; j < 4; ++j) {
            const int tg = tt0 + wm + rt * 16 + prow[j];
            if (tg < tend) {
                double* dst = cur + ((size_t)(tg - t0) * NB + b) * NO + o0 + wn;
#pragma unroll
                for (int ct = 0; ct < 4; ++ct)
                    dst[ct * 16 + pcol[j]] = acc[rt][ct][j];
            }
        }
    }
}

// LIF scan: one thread per (b,o); cur chunk is [tc][b*NO+o] fp64 (wave reads 512B
// contiguous per t-step). 32-step double buffer: next block's 32 loads are issued
// one full iteration before use -> ~8.4MB in flight across the grid (> BW*latency).
// Each thread stores 128B contiguous per iteration -> full-line writes.
#define NC 32
__global__ __launch_bounds__(64)
void snn_scan_f64(const double* __restrict__ cur, float* __restrict__ out,
                  double* __restrict__ vstate, int t0, int len)
{
    const int gid = blockIdx.x * 64 + threadIdx.x;   // b*NO + o
    const double dt = 0.001 / 50.0;                  // MS / TAU, IEEE double

    double v = (t0 == 0) ? 0.0 : vstate[gid];
    const double* cp = cur + gid;                    // stride NB*NO per t-step
    float* op = out + (size_t)gid * NT + t0;         // thread-contiguous in t

    const size_t ts = (size_t)NB * NO;               // 32768
    const int nb = len / NC;                         // full 32-blocks
    const int rem = len - nb * NC;                   // tail (multiple of 8)

    double A[NC], B[NC];
#pragma unroll
    for (int j = 0; j < NC; ++j) A[j] = (j < len) ? cp[(size_t)j * ts] : 0.0;

    for (int blk = 0; blk < nb; ++blk) {
        const int next = (blk + 1) * NC;
#pragma unroll
        for (int j = 0; j < NC; ++j)
            B[j] = (next + j < len) ? cp[(size_t)(next + j) * ts] : 0.0;

#pragma unroll
        for (int q = 0; q < NC; q += 8) {
            float s[8];
#pragma unroll
            for (int j = 0; j < 8; ++j) {
                v = v + (A[q + j] - v) * dt;
                const bool sp = (v >= 1.0);
                s[j] = sp ? 1.0f : 0.0f;
                if (sp) v = 0.0;
            }
            *(float4*)(op + q)     = make_float4(s[0], s[1], s[2], s[3]);
            *(float4*)(op + q + 4) = make_float4(s[4], s[5], s[6], s[7]);
        }
        op += NC;
#pragma unroll
        for (int j = 0; j < NC; ++j) A[j] = B[j];
    }

    for (int q = 0; q < rem; q += 8) {               // tail (data already in A)
        float s[8];
#pragma unroll
        for (int j = 0; j < 8; ++j) {
            v = v + (A[q + j] - v) * dt;
            const bool sp = (v >= 1.0);
            s[j] = sp ? 1.0f : 0.0f;
            if (sp) v = 0.0;
        }
        *(float4*)(op + q)     = make_float4(s[0], s[1], s[2], s[3]);
        *(float4*)(op + q + 4) = make_float4(s[4], s[5], s[6], s[7]);
    }
    vstate[gid] = v;
}

extern "C" void kernel_launch(void* const* d_in, const int* in_sizes, int n_in,
                              void* d_out, int out_size, void* d_ws, size_t ws_size,
                              hipStream_t stream)
{
    const float* x = (const float*)d_in[0];
    const float* w = (const float*)d_in[1];
    float* out = (float*)d_out;

    const size_t vbytes = (size_t)NB * NO * sizeof(double);   // 256 KB
    double* vstate = (double*)d_ws;
    double* curbuf = (double*)((char*)d_ws + vbytes);

    const size_t per_t = (size_t)NB * NO * sizeof(double);    // 256 KB per t-step
    size_t avail = (ws_size > vbytes) ? (ws_size - vbytes) : 0;
    int Tc = (int)((avail / per_t < (size_t)NT) ? (avail / per_t) : (size_t)NT);
    Tc &= ~7;                 // multiple of 8 (scan tail granularity)
    if (Tc < 8) Tc = 8;

    for (int t0 = 0; t0 < NT; t0 += Tc) {
        const int len = (NT - t0 < Tc) ? (NT - t0) : Tc;
        dim3 gg((len + TT - 1) / TT, NO / OT, NB);
        snn_gemm_mfma64<<<gg, 256, 0, stream>>>(x, w, curbuf, t0, len);
        snn_scan_f64<<<(NB * NO) / 64, 64, 0, stream>>>(curbuf, out, vstate, t0, len);
    }
}